// Round 14
// baseline (68.924 us; speedup 1.0000x reference)
//
#include <hip/hip_runtime.h>

#define E_TOTAL 320000
#define NNODES  10000
#define HID     256
#define NCLS    10

typedef __attribute__((ext_vector_type(4))) float f32x4;
typedef __attribute__((ext_vector_type(2))) float f32x2;
typedef __attribute__((ext_vector_type(4))) unsigned int u32x4;
typedef __attribute__((ext_vector_type(8))) __bf16 bf16x8;
typedef __attribute__((ext_vector_type(8))) unsigned short u16x8;

static __device__ __forceinline__ unsigned short f2bf(float f) {
  unsigned u = __builtin_bit_cast(unsigned, f);
  u += 0x7fffu + ((u >> 16) & 1u);
  return (unsigned short)(u >> 16);
}

// ---- prep: W1 -> bf16 B-frags | W2 -> bf16 B-frags (padded cols) ----
__global__ void k_pack(const float* __restrict__ W1,
                       const float* __restrict__ W2,
                       unsigned short* __restrict__ w1f,
                       unsigned short* __restrict__ w2f) {
  int b = blockIdx.x, tid = threadIdx.x;
  if (b < 64) {
    int gid = b * 256 + tid;                      // 16384
    int l = gid & 63, kk = (gid >> 6) & 7, cb = (gid >> 9) & 15, half = gid >> 13;
    int kbase = half * 256 + kk * 32 + (l >> 4) * 8;
    int col = cb * 16 + (l & 15);
    u16x8 o;
#pragma unroll
    for (int j = 0; j < 8; ++j) o[j] = f2bf(W1[(size_t)(kbase + j) * HID + col]);
    *((u16x8*)w1f + gid) = o;
  } else {
    int gid = (b - 64) * 256 + tid;               // 512
    int l = gid & 63, kk = gid >> 6;
    int kbase = kk * 32 + (l >> 4) * 8;
    int c = l & 15;
    u16x8 o;
#pragma unroll
    for (int j = 0; j < 8; ++j)
      o[j] = (c < NCLS) ? f2bf(W2[(size_t)(kbase + j) * NCLS + c]) : (unsigned short)0;
    *((u16x8*)w2f + gid) = o;
  }
}

// ---- node GEMM, x-conversion fused: Y = x@W1 (+b1), fp8, fragment-permuted.
// Stages RAW f32 rows via global_load_lds with 32B-unit XOR swizzle
// (unit u ^= row&7; inverse applied to per-lane global source).
// Block = 32 nodes x ALL 512 cols (both halves). Wave wv covers cols
// [wv*128, wv*128+128), half = wv>>1.
__global__ __launch_bounds__(256, 3) void k_prep(
    const float* __restrict__ x,
    const unsigned short* __restrict__ w1f,
    const float* __restrict__ b1,
    unsigned char* __restrict__ Yf8)           // [NNODES][512] fp8
{
  __shared__ __align__(16) float ldsX[2][32 * 64];   // 2 x 8 KB f32

  const int tid  = threadIdx.x;
  const int lane = tid & 63;
  const int wv   = tid >> 6;
  const int n0   = blockIdx.x * 32;
  const int l15  = lane & 15;
  const int lhi  = lane >> 4;
  const int half = wv >> 1;

  f32x4 acc[2][8] = {};   // [m][n]

  auto stageX = [&](int kb, int buf) {
#pragma unroll
    for (int i = 0; i < 2; ++i) {
      int row = i * 16 + wv * 4 + (lane >> 4);     // 0..31
      int gr = n0 + row; if (gr > NNODES - 1) gr = NNODES - 1;
      int c = lane & 15;                           // 16B chunk within 256B row
      int csrc = ((((c >> 1) ^ (row & 7)) << 1) | (c & 1));  // inverse of 32B-unit swz
      const float* g = x + (size_t)gr * HID + kb * 64 + csrc * 4;
      float* lp = &ldsX[buf][(i * 16 + wv * 4) * 64];
      __builtin_amdgcn_global_load_lds(
          (const __attribute__((address_space(1))) unsigned int*)g,
          (__attribute__((address_space(3))) unsigned int*)lp,
          16, 0, 0);
    }
  };

  stageX(0, 0);

  for (int kb = 0; kb < 4; ++kb) {
    int buf = kb & 1;
    __syncthreads();
    if (kb < 3) stageX(kb + 1, buf ^ 1);

#pragma unroll
    for (int ks = 0; ks < 2; ++ks) {
      // A frags: row = m*16+l15, k-range = ks*32 + lhi*8 (one 32B unit, swizzled)
      bf16x8 afr[2];
#pragma unroll
      for (int m = 0; m < 2; ++m) {
        int row = m * 16 + l15;
        int u = (ks * 4 + lhi) ^ (row & 7);
        const float* p = &ldsX[buf][0] + row * 64 + u * 8;
        f32x4 lo = *(const f32x4*)p;
        f32x4 hi = *(const f32x4*)(p + 4);
        bf16x8 t;
        t[0] = (__bf16)lo[0]; t[1] = (__bf16)lo[1];
        t[2] = (__bf16)lo[2]; t[3] = (__bf16)lo[3];
        t[4] = (__bf16)hi[0]; t[5] = (__bf16)hi[1];
        t[6] = (__bf16)hi[2]; t[7] = (__bf16)hi[3];
        afr[m] = t;
      }
      int kk = kb * 2 + ks;
#pragma unroll
      for (int n = 0; n < 8; ++n) {
        int cb = (wv & 1) * 8 + n;
        int f = (half * 16 + cb) * 8 + kk;
        bf16x8 bfr = *(const bf16x8*)(w1f + ((size_t)f * 64 + lane) * 8);
#pragma unroll
        for (int m = 0; m < 2; ++m)
          acc[m][n] = __builtin_amdgcn_mfma_f32_16x16x32_bf16(afr[m], bfr, acc[m][n], 0, 0, 0);
      }
    }
  }

  float b1v[8];
#pragma unroll
  for (int n = 0; n < 8; ++n)
    b1v[n] = (half == 0) ? b1[(wv & 1) * 128 + n * 16 + l15] : 0.f;

#pragma unroll
  for (int m = 0; m < 2; ++m)
#pragma unroll
    for (int n = 0; n < 8; ++n) {
      int colg = wv * 128 + n * 16 + l15;
      int c = colg & 255;
      int pos = ((c >> 3) & 3) * 64 + ((c >> 5) << 3) + (c & 7);
#pragma unroll
      for (int r = 0; r < 4; ++r) {
        int row = m * 16 + lhi * 4 + r;
        int gr = n0 + row;
        if (gr < NNODES) {
          float v = acc[m][n][r] + b1v[n];
          int pk = __builtin_amdgcn_cvt_pk_fp8_f32(v, v, 0, false);
          Yf8[(size_t)gr * 512 + half * 256 + pos] = (unsigned char)(pk & 0xff);
        }
      }
    }
}

// ---- edge kernel (round-6 proven): gather fp8 Y (8 lines/edge), decode,
// add+relu, bf16 GEMM2 (K=256,N=16pad), log_softmax ----
__global__ __launch_bounds__(256, 4) void k_edge(
    const int* __restrict__ ei,
    const unsigned char* __restrict__ Yf8,
    const unsigned short* __restrict__ w2f,
    const float* __restrict__ b2,
    float* __restrict__ out)
{
  __shared__ __align__(16) unsigned short ldsW[4096];   // w2 frags, 8 KB

  const int tid  = threadIdx.x;
  const int lane = tid & 63;
  const int wv   = tid >> 6;
  const int e0   = blockIdx.x * 64;
  const int l15  = lane & 15;
  const int lhi  = lane >> 4;

  int edge = e0 + wv * 16 + l15;
  int src = ei[edge];
  int dst = ei[E_TOTAL + edge];

  {
    const u16x8* s = (const u16x8*)w2f;
    u16x8* d = (u16x8*)ldsW;
    d[tid] = s[tid];
    d[tid + 256] = s[tid + 256];
  }
  __syncthreads();

  // per lane: 64 contiguous bytes per side (fragment-permuted fp8)
  const u32x4* q1 = (const u32x4*)(Yf8 + (size_t)src * 512 + lhi * 64);
  const u32x4* q2 = (const u32x4*)(Yf8 + (size_t)dst * 512 + 256 + lhi * 64);
  u32x4 ya[4], yb[4];
#pragma unroll
  for (int i = 0; i < 4; ++i) { ya[i] = q1[i]; yb[i] = q2[i]; }

  f32x4 lg = {0.f, 0.f, 0.f, 0.f};
#pragma unroll
  for (int kk = 0; kk < 8; ++kk) {
    bf16x8 bw = *(const bf16x8*)(ldsW + kk * 512 + lane * 8);
    unsigned a0 = ya[kk >> 1][(kk & 1) * 2], a1 = ya[kk >> 1][(kk & 1) * 2 + 1];
    unsigned c0 = yb[kk >> 1][(kk & 1) * 2], c1 = yb[kk >> 1][(kk & 1) * 2 + 1];
    f32x2 A0 = __builtin_amdgcn_cvt_pk_f32_fp8(a0, false);
    f32x2 A1 = __builtin_amdgcn_cvt_pk_f32_fp8(a0, true);
    f32x2 A2 = __builtin_amdgcn_cvt_pk_f32_fp8(a1, false);
    f32x2 A3 = __builtin_amdgcn_cvt_pk_f32_fp8(a1, true);
    f32x2 B0 = __builtin_amdgcn_cvt_pk_f32_fp8(c0, false);
    f32x2 B1 = __builtin_amdgcn_cvt_pk_f32_fp8(c0, true);
    f32x2 B2 = __builtin_amdgcn_cvt_pk_f32_fp8(c1, false);
    f32x2 B3 = __builtin_amdgcn_cvt_pk_f32_fp8(c1, true);
    bf16x8 hh;
    hh[0] = (__bf16)fmaxf(A0[0] + B0[0], 0.f);
    hh[1] = (__bf16)fmaxf(A0[1] + B0[1], 0.f);
    hh[2] = (__bf16)fmaxf(A1[0] + B1[0], 0.f);
    hh[3] = (__bf16)fmaxf(A1[1] + B1[1], 0.f);
    hh[4] = (__bf16)fmaxf(A2[0] + B2[0], 0.f);
    hh[5] = (__bf16)fmaxf(A2[1] + B2[1], 0.f);
    hh[6] = (__bf16)fmaxf(A3[0] + B3[0], 0.f);
    hh[7] = (__bf16)fmaxf(A3[1] + B3[1], 0.f);
    lg = __builtin_amdgcn_mfma_f32_16x16x32_bf16(hh, bw, lg, 0, 0, 0);
  }

  // + b2, log_softmax across the 16-lane class group (cols 10..15 padding)
  bool valid = (l15 < NCLS);
  float bias = valid ? b2[l15] : 0.f;
#pragma unroll
  for (int r = 0; r < 4; ++r) {
    float v = lg[r] + bias;
    float mv = valid ? v : -1e30f;
#pragma unroll
    for (int s = 1; s < 16; s <<= 1) mv = fmaxf(mv, __shfl_xor(mv, s, 64));
    float ev = valid ? __expf(v - mv) : 0.f;
    float sv = ev;
#pragma unroll
    for (int s = 1; s < 16; s <<= 1) sv += __shfl_xor(sv, s, 64);
    float res = v - mv - __logf(sv);
    if (valid) out[(size_t)(e0 + wv * 16 + lhi * 4 + r) * NCLS + l15] = res;
  }
}

extern "C" void kernel_launch(void* const* d_in, const int* in_sizes, int n_in,
                              void* d_out, int out_size, void* d_ws, size_t ws_size,
                              hipStream_t stream) {
  const float* x  = (const float*)d_in[0];
  const int*   ei = (const int*)d_in[1];
  const float* W1 = (const float*)d_in[2];
  const float* b1 = (const float*)d_in[3];
  const float* W2 = (const float*)d_in[4];
  const float* b2 = (const float*)d_in[5];
  float* out = (float*)d_out;

  char* ws = (char*)d_ws;
  unsigned short* w1f = (unsigned short*)ws;             // 262,144 B
  unsigned short* w2f = (unsigned short*)(ws + 262144);  // 8,192 B
  unsigned char*  Yf8 = (unsigned char*)(ws + 270336);   // 5,120,000 B

  k_pack<<<66, 256, 0, stream>>>(W1, W2, w1f, w2f);
  k_prep<<<(NNODES + 31) / 32, 256, 0, stream>>>(x, w1f, b1, Yf8);
  k_edge<<<E_TOTAL / 64, 256, 0, stream>>>(ei, Yf8, w2f, b2, out);
}